// Round 3
// baseline (10400.948 us; speedup 1.0000x reference)
//
#include <hip/hip_runtime.h>
#include <math.h>

// Problem constants: S=512, B=64, I=512, H=1024, fp32.
#define RS 512
#define RB 64
#define RI 512
#define RH 1024

#define NG   8    // batch groups
#define WPG  32   // workgroups (j-slices) per group
#define BPG  8    // batches per group

// ---------------------------------------------------------------------------
// Kernel 1: Vx = x @ Vw^T + Vb   (unchanged — measured-correct)
// ---------------------------------------------------------------------------
__global__ __launch_bounds__(256) void vx_gemm(const float* __restrict__ A,
                                               const float* __restrict__ W,
                                               const float* __restrict__ bias,
                                               float* __restrict__ C,
                                               int M, int N, int K) {
    __shared__ __align__(16) float As[16][68];
    __shared__ __align__(16) float Bs[16][68];

    const int tx = threadIdx.x;
    const int ty = threadIdx.y;
    const int tid = ty * 16 + tx;
    const int m0 = blockIdx.y * 64;
    const int n0 = blockIdx.x * 64;

    float acc[4][4] = {};

    const int row  = tid >> 2;
    const int quad = tid & 3;

    for (int k0 = 0; k0 < K; k0 += 16) {
        float4 av = *(const float4*)&A[(size_t)(m0 + row) * K + k0 + quad * 4];
        float4 wv = *(const float4*)&W[(size_t)(n0 + row) * K + k0 + quad * 4];
        const int kq = quad * 4;
        As[kq + 0][row] = av.x; As[kq + 1][row] = av.y;
        As[kq + 2][row] = av.z; As[kq + 3][row] = av.w;
        Bs[kq + 0][row] = wv.x; Bs[kq + 1][row] = wv.y;
        Bs[kq + 2][row] = wv.z; Bs[kq + 3][row] = wv.w;
        __syncthreads();

        #pragma unroll
        for (int k = 0; k < 16; ++k) {
            float4 a = *(const float4*)&As[k][ty * 4];
            float4 b = *(const float4*)&Bs[k][tx * 4];
            float am[4] = {a.x, a.y, a.z, a.w};
            float bn[4] = {b.x, b.y, b.z, b.w};
            #pragma unroll
            for (int i = 0; i < 4; ++i)
                #pragma unroll
                for (int j = 0; j < 4; ++j)
                    acc[i][j] = fmaf(am[i], bn[j], acc[i][j]);
        }
        __syncthreads();
    }

    #pragma unroll
    for (int i = 0; i < 4; ++i) {
        const int m = m0 + ty * 4 + i;
        const int n = n0 + tx * 4;
        float4 o;
        o.x = acc[i][0] + bias[n + 0];
        o.y = acc[i][1] + bias[n + 1];
        o.z = acc[i][2] + bias[n + 2];
        o.w = acc[i][3] + bias[n + 3];
        *(float4*)&C[(size_t)m * N + n] = o;
    }
}

// ---------------------------------------------------------------------------
// Kernel 2: persistent recurrence, streamed chunk exchange (no group barrier).
//
// 256 WGs x 256 thr, 1 WG/CU. WG (g = bid&7, sub = bid>>3) owns j-slice
// [sub*32,+32) for batches [g*8,+8). Ww slice in registers (128 VGPR/thr).
//
// h exchange: 32 chunks per group per step; chunk p = h[k=p*32..+32)[8b],
// layout [k32][b8] (1KB). Wave w consumes exactly chunks [8w, 8w+8):
//   poll 32 seq words (one coalesced load) -> 8 pipelined global loads ->
//   private LDS region (no cross-wave sharing, no barrier).
// Producer wave publishes its hex quarter + RELEASE-stores its own seq word
// (wave-level vmcnt drain). Only barrier per step: before the k-reduce.
// Red is parity double-buffered so waves may free-run +-1 step.
// ---------------------------------------------------------------------------
__global__ __launch_bounds__(256, 1) void rnn_persistent(
    const float* __restrict__ Ww, const float* __restrict__ Wb,
    float* __restrict__ hseq, float* __restrict__ hfin,
    float* __restrict__ hex, int* __restrict__ seq)
{
    const int tid = threadIdx.x;
    const int g   = blockIdx.x & 7;
    const int sub = blockIdx.x >> 3;
    const int j0  = sub * 32;
    const int b0  = g * BPG;

    const int w    = tid >> 6;       // wave 0..3
    const int lane = tid & 63;
    const int kc   = w * 4 + (lane >> 4);   // 0..15 : owns k in [kc*64, +64)
    const int kc_l = lane >> 4;             // 0..3
    const int jp   = lane & 15;             // j-pair

    const int o_jl = tid & 31, o_bl = tid >> 5;   // epilogue output (j, b)
    const int oj = j0 + o_jl;

    // Ww[j0+jp*2 .. +1][kc*64 .. +63] -> 128 VGPRs.
    float wreg[2][64];
    {
        const float* base = Ww + (size_t)(j0 + jp * 2) * RH + kc * 64;
        #pragma unroll
        for (int jj = 0; jj < 2; ++jj)
            #pragma unroll
            for (int ki = 0; ki < 64; ki += 4) {
                float4 v = *(const float4*)(base + (size_t)jj * RH + ki);
                wreg[jj][ki + 0] = v.x; wreg[jj][ki + 1] = v.y;
                wreg[jj][ki + 2] = v.z; wreg[jj][ki + 3] = v.w;
            }
    }
    const float wb = Wb[oj];

    // Hs: per-wave private region, 2080 floats. Layout [kc_l][k64][b8] with
    // +4 float stagger per kc_l (stride 516) -> FMA reads hit 4 distinct
    // bank-quads x 16-lane broadcast = conflict-free.
    __shared__ __align__(16) float Hs[4 * 2080];
    // Red: parity-double-buffered k-split partials, rotation-swizzled slots.
    __shared__ __align__(16) float Red[2 * 4096];

    for (int t = 0; t < RS; ++t) {
        float* cell = hseq + (size_t)t * (RB * RH) + (size_t)(b0 + o_bl) * RH + oj;
        const float vx = *cell;   // prefetch; consumed in epilogue

        if (t > 0) {
            // ---- poll: my wave's 32 seq words in one coalesced load ----
            const int* sq = seq + g * 128 + w * 32;
            int v;
            do {
                v = 0x7fffffff;
                if (lane < 32)
                    v = __hip_atomic_load(sq + lane, __ATOMIC_RELAXED,
                                          __HIP_MEMORY_SCOPE_AGENT);
            } while (!__all(v >= t));

            // ---- load 8 chunks (pipelined), stage to private LDS ----
            const unsigned long long* src = (const unsigned long long*)
                (hex + (((size_t)((t - 1) & 1)) * NG + g) * 8192)
                + (size_t)w * 1024 + lane * 2;
            unsigned long long dlo[8], dhi[8];
            #pragma unroll
            for (int c = 0; c < 8; ++c) {
                dlo[c] = __hip_atomic_load(src + c * 128,     __ATOMIC_RELAXED,
                                           __HIP_MEMORY_SCOPE_AGENT);
                dhi[c] = __hip_atomic_load(src + c * 128 + 1, __ATOMIC_RELAXED,
                                           __HIP_MEMORY_SCOPE_AGENT);
            }
            float* wbase = &Hs[w * 2080];
            #pragma unroll
            for (int c = 0; c < 8; ++c) {
                union { unsigned long long u[2]; float4 f; } cv;
                cv.u[0] = dlo[c]; cv.u[1] = dhi[c];
                *(float4*)&wbase[(c >> 1) * 516 + (c & 1) * 256 + lane * 4] = cv.f;
            }

            // ---- FMA over my 64-k range ----
            float acc[16];
            #pragma unroll
            for (int i = 0; i < 16; ++i) acc[i] = 0.f;
            const float4* hv = (const float4*)&Hs[w * 2080 + kc_l * 516];
            #pragma unroll
            for (int ki = 0; ki < 64; ++ki) {
                const float4 h0 = hv[ki * 2];
                const float4 h1 = hv[ki * 2 + 1];
                const float w0 = wreg[0][ki], w1 = wreg[1][ki];
                acc[0]  = fmaf(w0, h0.x, acc[0]);  acc[1]  = fmaf(w0, h0.y, acc[1]);
                acc[2]  = fmaf(w0, h0.z, acc[2]);  acc[3]  = fmaf(w0, h0.w, acc[3]);
                acc[4]  = fmaf(w0, h1.x, acc[4]);  acc[5]  = fmaf(w0, h1.y, acc[5]);
                acc[6]  = fmaf(w0, h1.z, acc[6]);  acc[7]  = fmaf(w0, h1.w, acc[7]);
                acc[8]  = fmaf(w1, h0.x, acc[8]);  acc[9]  = fmaf(w1, h0.y, acc[9]);
                acc[10] = fmaf(w1, h0.z, acc[10]); acc[11] = fmaf(w1, h0.w, acc[11]);
                acc[12] = fmaf(w1, h1.x, acc[12]); acc[13] = fmaf(w1, h1.y, acc[13]);
                acc[14] = fmaf(w1, h1.z, acc[14]); acc[15] = fmaf(w1, h1.w, acc[15]);
            }

            // ---- partials -> Red (rotation swizzle; <=2-way banks) ----
            float* rp = &Red[(t & 1) * 4096 + (kc * 16 + jp) * 16];
            const int rot = (jp >> 1) + ((kc & 1) << 3);
            #pragma unroll
            for (int v2 = 0; v2 < 16; ++v2)
                rp[(v2 + rot) & 15] = acc[v2];
            __syncthreads();   // the only barrier in the step
        }

        // ---- epilogue: 16-way k reduce + bias + Vx + tanh ----
        float z = 0.f;
        if (t > 0) {
            const int vidx = (o_jl & 1) * 8 + o_bl;
            const int rbse = (t & 1) * 4096;
            const int jrow = o_jl >> 1;
            #pragma unroll
            for (int kk = 0; kk < 16; ++kk)
                z += Red[rbse + (kk * 16 + jrow) * 16 +
                         ((vidx + (o_jl >> 2) + ((kk & 1) << 3)) & 15)];
        }
        const float h = tanhf(z + wb + vx);
        __builtin_nontemporal_store(h, cell);

        if (t == RS - 1) {
            hfin[(size_t)(b0 + o_bl) * RH + oj] = h;
        } else {
            // publish my element of chunk `sub` ([k32][b8] layout)
            __hip_atomic_store(
                hex + (((size_t)(t & 1)) * NG + g) * 8192 + sub * 256 + o_jl * 8 + o_bl,
                h, __ATOMIC_RELAXED, __HIP_MEMORY_SCOPE_AGENT);
            // per-wave release: waits this wave's stores (vmcnt), then flags
            if (lane == 0)
                __hip_atomic_store(seq + g * 128 + sub * 4 + w, t + 1,
                                   __ATOMIC_RELEASE, __HIP_MEMORY_SCOPE_AGENT);
        }
    }
}

// ---------------------------------------------------------------------------
extern "C" void kernel_launch(void* const* d_in, const int* in_sizes, int n_in,
                              void* d_out, int out_size, void* d_ws, size_t ws_size,
                              hipStream_t stream) {
    const float* x  = (const float*)d_in[0];  // (S,B,I)
    const float* Ww = (const float*)d_in[1];  // (H,H)
    const float* Wb = (const float*)d_in[2];  // (H)
    const float* Vw = (const float*)d_in[3];  // (H,I)
    const float* Vb = (const float*)d_in[4];  // (H)

    float* out  = (float*)d_out;
    float* hseq = out;                                  // (S,B,H)
    float* hfin = out + (size_t)RS * RB * RH;           // (B,H)

    // ws: [seq: 8*32*4 ints = 4KB][pad][hex: 2*8*8192 floats = 512KB]
    int*   seq = (int*)d_ws;
    float* hex = (float*)((char*)d_ws + 8192);

    // 1) Vx = x @ Vw^T + Vb  -> hseq (consumed in place by recurrence)
    {
        dim3 grid(RH / 64, (RS * RB) / 64);
        dim3 block(16, 16);
        vx_gemm<<<grid, block, 0, stream>>>(x, Vw, Vb, hseq, RS * RB, RH, RI);
    }

    // 2) Persistent recurrence, streamed exchange.
    rnn_persistent<<<dim3(NG * WPG), dim3(256), 0, stream>>>(Ww, Wb, hseq, hfin,
                                                             hex, seq);
}